// Round 11
// baseline (401.708 us; speedup 1.0000x reference)
//
#include <hip/hip_runtime.h>
#include <hip/hip_bf16.h>
#include <math.h>

typedef __hip_bfloat16 bf16;
typedef __attribute__((ext_vector_type(8))) short short8;
typedef __attribute__((ext_vector_type(4))) float f32x4;

#define MFMA16(A, B, C) __builtin_amdgcn_mfma_f32_16x16x32_bf16((A), (B), (C), 0, 0, 0)
#define NEG_BIG (-1e30f)

// DPP row_ror rotate within 16-lane rows (VALU pipe — NOT LDS, unlike __shfl)
#define DPP_F(x, ctrl) \
    __int_as_float(__builtin_amdgcn_update_dpp(0, __float_as_int(x), (ctrl), 0xf, 0xf, false))

static __device__ __forceinline__ float rowsum16(float x) {
    x += DPP_F(x, 0x121);
    x += DPP_F(x, 0x122);
    x += DPP_F(x, 0x124);
    x += DPP_F(x, 0x128);
    return x;
}
static __device__ __forceinline__ float rowmax16(float x) {
    x = fmaxf(x, DPP_F(x, 0x121));
    x = fmaxf(x, DPP_F(x, 0x122));
    x = fmaxf(x, DPP_F(x, 0x124));
    x = fmaxf(x, DPP_F(x, 0x128));
    return x;
}

// async global->LDS, 16 B per lane; LDS dest = wave-uniform base + lane*16
static __device__ __forceinline__ void glds16(const bf16* g, short* l) {
    __builtin_amdgcn_global_load_lds(
        (const __attribute__((address_space(1))) void*)g,
        (__attribute__((address_space(3))) void*)l,
        16, 0, 0);
}

// fp32 -> bf16 round-to-nearest-even via bit ops
static __device__ __forceinline__ unsigned short f32_to_bf16_rne(float f) {
    unsigned int u = __float_as_uint(f);
    unsigned int rnd = 0x7FFFu + ((u >> 16) & 1u);
    return (unsigned short)((u + rnd) >> 16);
}

// In-kernel dtype detection (wave-uniform): scan first 64 shorts of x.
static __device__ __forceinline__ bool inputs_are_fp32(const unsigned short* x16) {
    int lane = threadIdx.x & 63;
    int e = (x16[lane] >> 7) & 0xFF;
    unsigned long long ball = __ballot(e >= 133);
    return __popcll(ball) >= 4;
}

// ---------------------------------------------------------------------------
// Kernel 0: canonical bf16 copies of all 5 inputs (fp32 path only).
// ---------------------------------------------------------------------------
__global__ __launch_bounds__(256) void convert_all(
    const void* __restrict__ xs, const void* __restrict__ wq,
    const void* __restrict__ wk, const void* __restrict__ wv,
    const void* __restrict__ wo,
    unsigned int* __restrict__ Xc, unsigned int* __restrict__ Wqc,
    unsigned int* __restrict__ Wkc, unsigned int* __restrict__ Wvc,
    unsigned int* __restrict__ Woc)
{
    if (!inputs_are_fp32((const unsigned short*)xs)) return;
    int i = blockIdx.x * 256 + threadIdx.x;  // 0 .. 4194303
    const float* src;
    unsigned int* dst;
    int off;
    if (i < 2097152) { src = (const float*)xs; dst = Xc; off = i; }
    else {
        int j = i - 2097152;
        int t = j >> 19;          // 0..3
        off = j & 524287;
        src = (const float*)((t == 0) ? wq : (t == 1) ? wk : (t == 2) ? wv : wo);
        dst = (t == 0) ? Wqc : (t == 1) ? Wkc : (t == 2) ? Wvc : Woc;
    }
    unsigned int lo = f32_to_bf16_rne(src[2 * off]);
    unsigned int hi = f32_to_bf16_rne(src[2 * off + 1]);
    dst[off] = (hi << 16) | lo;
}

// ---------------------------------------------------------------------------
// Kernel 1: QKV projection GEMM, m97-style 128x128 tile, BK=32,
// global_load_lds(16B) staging (no ds_write, no VGPR round-trip).
// grid = (32 m-tiles, 24 = 3 weights x 8 n-tiles), block = 256 (2x2 waves).
// Q,K: fused RoPE scalar stores [b,h,s,d]. V: LDS-transposed [b,h,d,s].
// ---------------------------------------------------------------------------
__global__ __launch_bounds__(256) void gemm_qkv_rope(
    const void* __restrict__ xr,
    const void* __restrict__ wqr, const void* __restrict__ wkr,
    const void* __restrict__ wvr,
    const bf16* __restrict__ Xc,
    const bf16* __restrict__ Wqc, const bf16* __restrict__ Wkc,
    const bf16* __restrict__ Wvc,
    const int* __restrict__ pos,
    bf16* __restrict__ Qb, bf16* __restrict__ Kb, bf16* __restrict__ Vt)
{
    const bool f32in = inputs_are_fp32((const unsigned short*)xr);
    const bf16* X = f32in ? Xc : (const bf16*)xr;

    // union: staging (As 4096 + Bs 4096 shorts) vs V-transpose tile 128x132
    __shared__ __align__(16) short smem[128 * 132];   // 33792 B
    short* As = smem;            // [128][32] row-major, unpadded
    short* Bs = smem + 4096;     // [128][32]

    const int m0   = blockIdx.x * 128;
    const int wsel = blockIdx.y >> 3;            // 0=Q, 1=K, 2=V
    const int n0   = (blockIdx.y & 7) * 128;
    const bf16* W  = (wsel == 0) ? (f32in ? Wqc : (const bf16*)wqr)
                   : (wsel == 1) ? (f32in ? Wkc : (const bf16*)wkr)
                                 : (f32in ? Wvc : (const bf16*)wvr);

    const int tid  = threadIdx.x;
    const int lane = tid & 63;
    const int wave = tid >> 6;
    const int wr   = wave >> 1, wc = wave & 1;   // 2x2 waves, each 64x64
    const int m    = lane & 15;
    const int q    = lane >> 4;

    // staging: wave stages rows [wave*32, wave*32+32) of both tiles,
    // 2 issues of 16 rows each; lane i -> row i/4, col-seg (i%4)*8.
    const int lrow = lane >> 2;           // 0..15
    const int lseg = (lane & 3) * 8;      // 0,8,16,24
    const bf16* Ag = X + (m0 + wave * 32 + lrow) * 1024 + lseg;       // +j*16*1024 +k0
    const bf16* Bg = W + (n0 + wave * 32 + lrow) * 1024 + lseg;
    short* Al = As + wave * 1024;         // +j*512 (shorts); lane off auto
    short* Bl = Bs + wave * 1024;

    f32x4 acc[4][4];
    for (int mi = 0; mi < 4; ++mi)
        for (int ni = 0; ni < 4; ++ni)
            acc[mi][ni] = (f32x4){0.f, 0.f, 0.f, 0.f};

    for (int k0 = 0; k0 < 1024; k0 += 32) {
        __syncthreads();                  // prior frag reads done
        glds16(Ag + k0,             Al);
        glds16(Ag + k0 + 16 * 1024, Al + 512);
        glds16(Bg + k0,             Bl);
        glds16(Bg + k0 + 16 * 1024, Bl + 512);
        __syncthreads();                  // barrier drains vmcnt -> tiles ready

        short8 af[4], bf[4];
        for (int mi = 0; mi < 4; ++mi)
            af[mi] = *(const short8*)&As[(wr * 64 + mi * 16 + m) * 32 + q * 8];
        for (int ni = 0; ni < 4; ++ni)
            bf[ni] = *(const short8*)&Bs[(wc * 64 + ni * 16 + m) * 32 + q * 8];
        for (int mi = 0; mi < 4; ++mi)
            for (int ni = 0; ni < 4; ++ni)
                acc[mi][ni] = MFMA16(af[mi], bf[ni], acc[mi][ni]);
    }

    const int bb = m0 >> 11;          // batch (block tile within one b)
    const int s0 = m0 & 2047;
    const int hh0 = n0 >> 6;          // first head of the 2 in this n-tile

    if (wsel < 2) {
        bf16* dstb = (wsel == 0) ? Qb : Kb;
        for (int mi = 0; mi < 4; ++mi)
            for (int ni = 0; ni < 4; ++ni)
                for (int r = 0; r < 4; ++r) {
                    int s = s0 + wr * 64 + mi * 16 + q * 4 + r;
                    int gn = n0 + wc * 64 + ni * 16 + m;
                    int h = gn >> 6, d = gn & 63;
                    float v = acc[mi][ni][r];
                    float partner = __shfl_xor(v, 1);
                    int   p    = d >> 1;
                    float freq = __expf((float)p * -0.28782313662425575f);
                    float ang  = (float)pos[s] * freq;
                    float sn, c;
                    sincosf(ang, &sn, &c);
                    float outv = ((d & 1) == 0) ? (c * v - sn * partner)
                                                : (sn * partner + c * v);
                    dstb[((bb * 16 + h) * 2048 + s) * 64 + d] = __float2bfloat16(outv);
                }
    } else {
        // V: transpose whole 128x128 tile through LDS (stride 132), then
        // coalesced [b,h,d,s] stores (2 threads per d-row, 128 B each).
        __syncthreads();   // all As/Bs frag reads done before alias overwrite
        for (int mi = 0; mi < 4; ++mi)
            for (int ni = 0; ni < 4; ++ni)
                for (int r = 0; r < 4; ++r) {
                    int ls = wr * 64 + mi * 16 + q * 4 + r;   // local s 0..127
                    int ld = wc * 64 + ni * 16 + m;           // local d 0..127
                    bf16 hv = __float2bfloat16(acc[mi][ni][r]);
                    smem[ld * 132 + ls] = *(short*)&hv;
                }
        __syncthreads();
        int dd = tid >> 1;            // 0..127 (head hh0 + dd>>6, d = dd&63)
        int half = tid & 1;           // s half: 64 shorts
        bf16* vrow = Vt + ((bb * 16 + hh0 + (dd >> 6)) * 64 + (dd & 63)) * 2048
                        + s0 + half * 64;
        for (int j = 0; j < 8; ++j)
            *(short8*)(vrow + j * 8) =
                *(const short8*)&smem[dd * 132 + half * 64 + j * 8];
    }
}

// ---------------------------------------------------------------------------
// Kernel 2: causal flash attention (unchanged from round 10).
// ---------------------------------------------------------------------------
#define KST 72
#define VST 136

__global__ __launch_bounds__(256) void flash_attn(
    const bf16* __restrict__ Qb, const bf16* __restrict__ Kb,
    const bf16* __restrict__ Vt, bf16* __restrict__ ctx)
{
    const int pair = blockIdx.x;      // 0..15
    const int h = blockIdx.y, b = blockIdx.z;
    const int bh = b * 16 + h;

    __shared__ __align__(16) short Ks[128 * KST];
    __shared__ __align__(16) short Vs[64 * VST];
    __shared__ __align__(16) short Ps[4][16 * VST];

    const int tid  = threadIdx.x;
    const int lane = tid & 63;
    const int wave = tid >> 6;
    const int m = lane & 15;
    const int q = lane >> 4;

    const int krow = tid >> 1;
    const int kseg = (tid & 1) * 32;
    const int vrow = tid >> 2;
    const int vseg = (tid & 3) * 32;

    const bf16* Kg = Kb + bh * 2048 * 64 + krow * 64   + kseg;
    const bf16* Vg = Vt + bh * 64 * 2048 + vrow * 2048 + vseg;

    for (int part = 0; part < 2; ++part) {
        const int qtile = (part == 0) ? pair : 31 - pair;
        const int nk2 = (qtile + 2) >> 1;
        const int rowbase = qtile * 64 + wave * 16;

        const bf16* Qp = Qb + (bh * 2048 + qtile * 64 + wave * 16 + m) * 64;
        short8 qf0 = *(const short8*)(Qp + q * 8);
        short8 qf1 = *(const short8*)(Qp + 32 + q * 8);

        f32x4 oacc[4];
        for (int nb = 0; nb < 4; ++nb) oacc[nb] = (f32x4){0.f, 0.f, 0.f, 0.f};
        float mi[4], li[4];
        for (int r = 0; r < 4; ++r) { mi[r] = NEG_BIG; li[r] = 0.f; }

        short8 kr[4], vr[4];
        for (int j = 0; j < 4; ++j) {
            kr[j] = *(const short8*)(Kg + j * 8);
            vr[j] = *(const short8*)(Vg + j * 8);
        }

        for (int kt2 = 0; kt2 < nk2; ++kt2) {
            __syncthreads();
            for (int j = 0; j < 4; ++j) {
                *(short8*)&Ks[krow * KST + kseg + j * 8] = kr[j];
                *(short8*)&Vs[vrow * VST + vseg + j * 8] = vr[j];
            }
            __syncthreads();

            if (kt2 + 1 < nk2) {
                for (int j = 0; j < 4; ++j) {
                    kr[j] = *(const short8*)(Kg + (kt2 + 1) * 8192 + j * 8);
                    vr[j] = *(const short8*)(Vg + (kt2 + 1) * 128  + j * 8);
                }
            }

            f32x4 sacc[8];
            for (int nc = 0; nc < 8; ++nc) {
                short8 kf0 = *(const short8*)&Ks[(nc * 16 + m) * KST + q * 8];
                short8 kf1 = *(const short8*)&Ks[(nc * 16 + m) * KST + 32 + q * 8];
                f32x4 z = {0.f, 0.f, 0.f, 0.f};
                z = MFMA16(qf0, kf0, z);
                z = MFMA16(qf1, kf1, z);
                sacc[nc] = z;
            }

            for (int nc = 0; nc < 8; ++nc)
                for (int r = 0; r < 4; ++r)
                    sacc[nc][r] *= 0.125f;
            if (kt2 * 128 + 127 > rowbase) {
                for (int nc = 0; nc < 8; ++nc)
                    for (int r = 0; r < 4; ++r) {
                        int row = rowbase + q * 4 + r;
                        int col = kt2 * 128 + nc * 16 + m;
                        if (col > row) sacc[nc][r] = NEG_BIG;
                    }
            }

            float mnew[4], alpha[4];
            for (int r = 0; r < 4; ++r) {
                float rm = sacc[0][r];
                for (int nc = 1; nc < 8; ++nc) rm = fmaxf(rm, sacc[nc][r]);
                rm = rowmax16(rm);
                mnew[r]  = fmaxf(mi[r], rm);
                alpha[r] = __expf(fmaxf(mi[r] - mnew[r], -80.f));
                mi[r]    = mnew[r];
            }
            for (int r = 0; r < 4; ++r) {
                float acc = 0.f;
                for (int nc = 0; nc < 8; ++nc) {
                    float p = __expf(fmaxf(sacc[nc][r] - mnew[r], -80.f));
                    sacc[nc][r] = p;
                    acc += p;
                }
                acc = rowsum16(acc);
                li[r] = li[r] * alpha[r] + acc;
                for (int nb = 0; nb < 4; ++nb) oacc[nb][r] *= alpha[r];
            }

            for (int nc = 0; nc < 8; ++nc)
                for (int r = 0; r < 4; ++r) {
                    bf16 hv = __float2bfloat16(sacc[nc][r]);
                    Ps[wave][(q * 4 + r) * VST + nc * 16 + m] = *(short*)&hv;
                }
            short8 pa[4];
            for (int ck = 0; ck < 4; ++ck)
                pa[ck] = *(const short8*)&Ps[wave][m * VST + ck * 32 + q * 8];

            for (int nb = 0; nb < 4; ++nb)
                for (int ck = 0; ck < 4; ++ck) {
                    short8 vf = *(const short8*)&Vs[(nb * 16 + m) * VST + ck * 32 + q * 8];
                    oacc[nb] = MFMA16(pa[ck], vf, oacc[nb]);
                }
        }

        for (int r = 0; r < 4; ++r) {
            float inv = 1.f / li[r];
            int srowg = qtile * 64 + wave * 16 + q * 4 + r;
            for (int nb = 0; nb < 4; ++nb)
                ctx[(b * 2048 + srowg) * 1024 + h * 64 + nb * 16 + m] =
                    __float2bfloat16(oacc[nb][r] * inv);
        }
        __syncthreads();
    }
}

// ---------------------------------------------------------------------------
// Kernel 3: output projection, m97-style 128x128 tile + global_load_lds.
// grid = (32, 8), block = 256.
// ---------------------------------------------------------------------------
__global__ __launch_bounds__(256) void gemm_out(
    const bf16* __restrict__ A,
    const void* __restrict__ wor, const bf16* __restrict__ Woc,
    const void* __restrict__ xr,
    void* __restrict__ out)
{
    const bool f32in = inputs_are_fp32((const unsigned short*)xr);
    const bf16* W = f32in ? Woc : (const bf16*)wor;

    __shared__ __align__(16) short smem[8192];
    short* As = smem;
    short* Bs = smem + 4096;

    const int m0 = blockIdx.x * 128;
    const int n0 = blockIdx.y * 128;
    const int tid  = threadIdx.x;
    const int lane = tid & 63;
    const int wave = tid >> 6;
    const int wr = wave >> 1, wc = wave & 1;
    const int m = lane & 15, q = lane >> 4;

    const int lrow = lane >> 2;
    const int lseg = (lane & 3) * 8;
    const bf16* Ag = A + (m0 + wave * 32 + lrow) * 1024 + lseg;
    const bf16* Bg = W + (n0 + wave * 32 + lrow) * 1024 + lseg;
    short* Al = As + wave * 1024;
    short* Bl = Bs + wave * 1024;

    f32x4 acc[4][4];
    for (int mi = 0; mi < 4; ++mi)
        for (int ni = 0; ni < 4; ++ni)
            acc[mi][ni] = (f32x4){0.f, 0.f, 0.f, 0.f};

    for (int k0 = 0; k0 < 1024; k0 += 32) {
        __syncthreads();
        glds16(Ag + k0,             Al);
        glds16(Ag + k0 + 16 * 1024, Al + 512);
        glds16(Bg + k0,             Bl);
        glds16(Bg + k0 + 16 * 1024, Bl + 512);
        __syncthreads();

        short8 af[4], bf[4];
        for (int mi = 0; mi < 4; ++mi)
            af[mi] = *(const short8*)&As[(wr * 64 + mi * 16 + m) * 32 + q * 8];
        for (int ni = 0; ni < 4; ++ni)
            bf[ni] = *(const short8*)&Bs[(wc * 64 + ni * 16 + m) * 32 + q * 8];
        for (int mi = 0; mi < 4; ++mi)
            for (int ni = 0; ni < 4; ++ni)
                acc[mi][ni] = MFMA16(af[mi], bf[ni], acc[mi][ni]);
    }

    for (int mi = 0; mi < 4; ++mi)
        for (int ni = 0; ni < 4; ++ni)
            for (int r = 0; r < 4; ++r) {
                int gm = m0 + wr * 64 + mi * 16 + q * 4 + r;
                int gn = n0 + wc * 64 + ni * 16 + m;
                int idx = gm * 1024 + gn;
                if (f32in) ((float*)out)[idx] = acc[mi][ni][r];
                else       ((bf16*)out)[idx]  = __float2bfloat16(acc[mi][ni][r]);
            }
}

// ---------------------------------------------------------------------------
extern "C" void kernel_launch(void* const* d_in, const int* in_sizes, int n_in,
                              void* d_out, int out_size, void* d_ws, size_t ws_size,
                              hipStream_t stream)
{
    const void* x_raw  = d_in[0];
    const void* Wq_raw = d_in[1];
    const void* Wk_raw = d_in[2];
    const void* Wv_raw = d_in[3];
    const void* Wo_raw = d_in[4];
    const int*  pos    = (const int*)d_in[5];

    char* ws = (char*)d_ws;
    bf16* Xc  = (bf16*)ws;                                    // 8 MB
    bf16* Wqc = (bf16*)(ws + 8388608);                        // 2 MB each
    bf16* Wkc = (bf16*)(ws + 8388608 + 2097152);
    bf16* Wvc = (bf16*)(ws + 8388608 + 2 * 2097152);
    bf16* Woc = (bf16*)(ws + 8388608 + 3 * 2097152);
    bf16* Qb  = (bf16*)(ws + 8388608 + 4 * 2097152);          // 8 MB each
    bf16* Kb  = Qb + 4194304;
    bf16* Vt  = Kb + 4194304;
    bf16* ctx = Vt + 4194304;

    convert_all<<<16384, 256, 0, stream>>>(
        x_raw, Wq_raw, Wk_raw, Wv_raw, Wo_raw,
        (unsigned int*)Xc, (unsigned int*)Wqc, (unsigned int*)Wkc,
        (unsigned int*)Wvc, (unsigned int*)Woc);

    gemm_qkv_rope<<<dim3(32, 24), 256, 0, stream>>>(
        x_raw, Wq_raw, Wk_raw, Wv_raw, Xc, Wqc, Wkc, Wvc, pos, Qb, Kb, Vt);
    flash_attn<<<dim3(16, 16, 2), 256, 0, stream>>>(Qb, Kb, Vt, ctx);
    gemm_out<<<dim3(32, 8), 256, 0, stream>>>(ctx, Wo_raw, Woc, x_raw, d_out);
}

// Round 12
// 220.588 us; speedup vs baseline: 1.8211x; 1.8211x over previous
//
#include <hip/hip_runtime.h>
#include <hip/hip_bf16.h>
#include <math.h>

typedef __hip_bfloat16 bf16;
typedef __attribute__((ext_vector_type(8))) short short8;
typedef __attribute__((ext_vector_type(4))) float f32x4;

#define MFMA16(A, B, C) __builtin_amdgcn_mfma_f32_16x16x32_bf16((A), (B), (C), 0, 0, 0)
#define NEG_BIG (-1e30f)

// DPP row_ror rotate within 16-lane rows (VALU pipe — NOT LDS, unlike __shfl)
#define DPP_F(x, ctrl) \
    __int_as_float(__builtin_amdgcn_update_dpp(0, __float_as_int(x), (ctrl), 0xf, 0xf, false))

static __device__ __forceinline__ float rowsum16(float x) {
    x += DPP_F(x, 0x121);
    x += DPP_F(x, 0x122);
    x += DPP_F(x, 0x124);
    x += DPP_F(x, 0x128);
    return x;
}
static __device__ __forceinline__ float rowmax16(float x) {
    x = fmaxf(x, DPP_F(x, 0x121));
    x = fmaxf(x, DPP_F(x, 0x122));
    x = fmaxf(x, DPP_F(x, 0x124));
    x = fmaxf(x, DPP_F(x, 0x128));
    return x;
}

// fp32 -> bf16 round-to-nearest-even via bit ops
static __device__ __forceinline__ unsigned short f32_to_bf16_rne(float f) {
    unsigned int u = __float_as_uint(f);
    unsigned int rnd = 0x7FFFu + ((u >> 16) & 1u);
    return (unsigned short)((u + rnd) >> 16);
}

// In-kernel dtype detection (wave-uniform): scan first 64 shorts of x.
static __device__ __forceinline__ bool inputs_are_fp32(const unsigned short* x16) {
    int lane = threadIdx.x & 63;
    int e = (x16[lane] >> 7) & 0xFF;
    unsigned long long ball = __ballot(e >= 133);
    return __popcll(ball) >= 4;
}

// ---------------------------------------------------------------------------
// Kernel 0a: RoPE cos/sin table [s][p] float2, 2048 x 32 entries (512 KB).
// 65K sincos once instead of 16M in the GEMM epilogue.
// ---------------------------------------------------------------------------
__global__ __launch_bounds__(256) void rope_table(
    const int* __restrict__ pos, float2* __restrict__ tab)
{
    int i = blockIdx.x * 256 + threadIdx.x;   // 0..65535
    int s = i >> 5, p = i & 31;
    float freq = __expf((float)p * -0.28782313662425575f);
    float ang  = (float)pos[s] * freq;
    float sn, c;
    sincosf(ang, &sn, &c);
    tab[i] = make_float2(c, sn);
}

// ---------------------------------------------------------------------------
// Kernel 0b: canonical bf16 copies of all 5 inputs (fp32 path only).
// ---------------------------------------------------------------------------
__global__ __launch_bounds__(256) void convert_all(
    const void* __restrict__ xs, const void* __restrict__ wq,
    const void* __restrict__ wk, const void* __restrict__ wv,
    const void* __restrict__ wo,
    unsigned int* __restrict__ Xc, unsigned int* __restrict__ Wqc,
    unsigned int* __restrict__ Wkc, unsigned int* __restrict__ Wvc,
    unsigned int* __restrict__ Woc)
{
    if (!inputs_are_fp32((const unsigned short*)xs)) return;
    int i = blockIdx.x * 256 + threadIdx.x;  // 0 .. 4194303
    const float* src;
    unsigned int* dst;
    int off;
    if (i < 2097152) { src = (const float*)xs; dst = Xc; off = i; }
    else {
        int j = i - 2097152;
        int t = j >> 19;          // 0..3
        off = j & 524287;
        src = (const float*)((t == 0) ? wq : (t == 1) ? wk : (t == 2) ? wv : wo);
        dst = (t == 0) ? Wqc : (t == 1) ? Wkc : (t == 2) ? Wvc : Woc;
    }
    unsigned int lo = f32_to_bf16_rne(src[2 * off]);
    unsigned int hi = f32_to_bf16_rne(src[2 * off + 1]);
    dst[off] = (hi << 16) | lo;
}

// ---------------------------------------------------------------------------
// Kernel 1: QKV projection GEMM (round-10 proven structure), RoPE via table.
// 64x64 tile, BK=32, ds_write staging + register prefetch.
// Q,K written [b,h,s,d]; V TRANSPOSED [b,h,d,s] via LDS.
// ---------------------------------------------------------------------------
__global__ __launch_bounds__(256) void gemm_qkv_rope(
    const void* __restrict__ xr,
    const void* __restrict__ wqr, const void* __restrict__ wkr,
    const void* __restrict__ wvr,
    const bf16* __restrict__ Xc,
    const bf16* __restrict__ Wqc, const bf16* __restrict__ Wkc,
    const bf16* __restrict__ Wvc,
    const float2* __restrict__ rtab,
    bf16* __restrict__ Qb, bf16* __restrict__ Kb, bf16* __restrict__ Vt)
{
    const bool f32in = inputs_are_fp32((const unsigned short*)xr);
    const bf16* X = f32in ? Xc : (const bf16*)xr;

    __shared__ __align__(16) short Xs[64 * 40];
    __shared__ __align__(16) short Ws[64 * 40];
    __shared__ __align__(16) short Ts[64 * 72];   // V transpose staging

    const int m0   = blockIdx.x * 64;
    const int wsel = blockIdx.y >> 4;            // 0=Q, 1=K, 2=V
    const int n0   = (blockIdx.y & 15) * 64;
    const bf16* W  = (wsel == 0) ? (f32in ? Wqc : (const bf16*)wqr)
                   : (wsel == 1) ? (f32in ? Wkc : (const bf16*)wkr)
                                 : (f32in ? Wvc : (const bf16*)wvr);

    const int tid  = threadIdx.x;
    const int lane = tid & 63;
    const int wave = tid >> 6;
    const int wr   = wave >> 1, wc = wave & 1;
    const int srow = tid >> 2;
    const int sseg = tid & 3;
    const int fr   = lane & 15;
    const int fq   = lane >> 4;

    const bf16* Xrow = X + (m0 + srow) * 1024 + sseg * 8;
    const bf16* Wrow = W + (n0 + srow) * 1024 + sseg * 8;

    f32x4 acc00 = {0.f,0.f,0.f,0.f}, acc01 = {0.f,0.f,0.f,0.f};
    f32x4 acc10 = {0.f,0.f,0.f,0.f}, acc11 = {0.f,0.f,0.f,0.f};

    short8 pxa = *(const short8*)(Xrow);   // prefetch k0 = 0
    short8 pwb = *(const short8*)(Wrow);

    for (int k0 = 0; k0 < 1024; k0 += 32) {
        __syncthreads();
        *(short8*)&Xs[srow * 40 + sseg * 8] = pxa;
        *(short8*)&Ws[srow * 40 + sseg * 8] = pwb;
        __syncthreads();
        if (k0 + 32 < 1024) {               // prefetch next tile (overlaps MFMA)
            pxa = *(const short8*)(Xrow + k0 + 32);
            pwb = *(const short8*)(Wrow + k0 + 32);
        }

        short8 a0 = *(const short8*)&Xs[(wr * 32 +      fr) * 40 + fq * 8];
        short8 a1 = *(const short8*)&Xs[(wr * 32 + 16 + fr) * 40 + fq * 8];
        short8 b0 = *(const short8*)&Ws[(wc * 32 +      fr) * 40 + fq * 8];
        short8 b1 = *(const short8*)&Ws[(wc * 32 + 16 + fr) * 40 + fq * 8];
        acc00 = MFMA16(a0, b0, acc00);
        acc01 = MFMA16(a0, b1, acc01);
        acc10 = MFMA16(a1, b0, acc10);
        acc11 = MFMA16(a1, b1, acc11);
    }

    const int bb = m0 >> 11;
    const int s0 = m0 & 2047;
    const int hh = n0 >> 6;

    if (wsel < 2) {
        for (int i = 0; i < 2; ++i)
            for (int j = 0; j < 2; ++j) {
                f32x4 a = (i == 0) ? ((j == 0) ? acc00 : acc01)
                                   : ((j == 0) ? acc10 : acc11);
                for (int r = 0; r < 4; ++r) {
                    int s = s0 + wr * 32 + i * 16 + fq * 4 + r;
                    int d = wc * 32 + j * 16 + fr;
                    float v = a[r];
                    float partner = __shfl_xor(v, 1);
                    float2 cs = rtab[s * 32 + (d >> 1)];
                    float outv = ((d & 1) == 0) ? (cs.x * v - cs.y * partner)
                                                : (cs.y * partner + cs.x * v);
                    bf16* dstb = (wsel == 0) ? Qb : Kb;
                    dstb[((bb * 16 + hh) * 2048 + s) * 64 + d] = __float2bfloat16(outv);
                }
            }
    } else {
        for (int i = 0; i < 2; ++i)
            for (int j = 0; j < 2; ++j) {
                f32x4 a = (i == 0) ? ((j == 0) ? acc00 : acc01)
                                   : ((j == 0) ? acc10 : acc11);
                for (int r = 0; r < 4; ++r) {
                    int ls = wr * 32 + i * 16 + fq * 4 + r;   // local s
                    int ld = wc * 32 + j * 16 + fr;           // local d
                    bf16 hv = __float2bfloat16(a[r]);
                    Ts[ld * 72 + ls] = *(short*)&hv;
                }
            }
        __syncthreads();
        int dd = tid >> 2;
        int sc = (tid & 3) * 16;
        short8 t0 = *(const short8*)&Ts[dd * 72 + sc];
        short8 t1 = *(const short8*)&Ts[dd * 72 + sc + 8];
        bf16* vrow = Vt + ((bb * 16 + hh) * 64 + dd) * 2048 + s0 + sc;
        *(short8*)(vrow)     = t0;
        *(short8*)(vrow + 8) = t1;
    }
}

// ---------------------------------------------------------------------------
// Kernel 2: causal flash attention (round-10 proven, unchanged).
// ---------------------------------------------------------------------------
#define KST 72
#define VST 136

__global__ __launch_bounds__(256) void flash_attn(
    const bf16* __restrict__ Qb, const bf16* __restrict__ Kb,
    const bf16* __restrict__ Vt, bf16* __restrict__ ctx)
{
    const int pair = blockIdx.x;      // 0..15
    const int h = blockIdx.y, b = blockIdx.z;
    const int bh = b * 16 + h;

    __shared__ __align__(16) short Ks[128 * KST];
    __shared__ __align__(16) short Vs[64 * VST];
    __shared__ __align__(16) short Ps[4][16 * VST];

    const int tid  = threadIdx.x;
    const int lane = tid & 63;
    const int wave = tid >> 6;
    const int m = lane & 15;
    const int q = lane >> 4;

    const int krow = tid >> 1;
    const int kseg = (tid & 1) * 32;
    const int vrow = tid >> 2;
    const int vseg = (tid & 3) * 32;

    const bf16* Kg = Kb + bh * 2048 * 64 + krow * 64   + kseg;
    const bf16* Vg = Vt + bh * 64 * 2048 + vrow * 2048 + vseg;

    for (int part = 0; part < 2; ++part) {
        const int qtile = (part == 0) ? pair : 31 - pair;
        const int nk2 = (qtile + 2) >> 1;
        const int rowbase = qtile * 64 + wave * 16;

        const bf16* Qp = Qb + (bh * 2048 + qtile * 64 + wave * 16 + m) * 64;
        short8 qf0 = *(const short8*)(Qp + q * 8);
        short8 qf1 = *(const short8*)(Qp + 32 + q * 8);

        f32x4 oacc[4];
        for (int nb = 0; nb < 4; ++nb) oacc[nb] = (f32x4){0.f, 0.f, 0.f, 0.f};
        float mi[4], li[4];
        for (int r = 0; r < 4; ++r) { mi[r] = NEG_BIG; li[r] = 0.f; }

        short8 kr[4], vr[4];
        for (int j = 0; j < 4; ++j) {
            kr[j] = *(const short8*)(Kg + j * 8);
            vr[j] = *(const short8*)(Vg + j * 8);
        }

        for (int kt2 = 0; kt2 < nk2; ++kt2) {
            __syncthreads();
            for (int j = 0; j < 4; ++j) {
                *(short8*)&Ks[krow * KST + kseg + j * 8] = kr[j];
                *(short8*)&Vs[vrow * VST + vseg + j * 8] = vr[j];
            }
            __syncthreads();

            if (kt2 + 1 < nk2) {
                for (int j = 0; j < 4; ++j) {
                    kr[j] = *(const short8*)(Kg + (kt2 + 1) * 8192 + j * 8);
                    vr[j] = *(const short8*)(Vg + (kt2 + 1) * 128  + j * 8);
                }
            }

            f32x4 sacc[8];
            for (int nc = 0; nc < 8; ++nc) {
                short8 kf0 = *(const short8*)&Ks[(nc * 16 + m) * KST + q * 8];
                short8 kf1 = *(const short8*)&Ks[(nc * 16 + m) * KST + 32 + q * 8];
                f32x4 z = {0.f, 0.f, 0.f, 0.f};
                z = MFMA16(qf0, kf0, z);
                z = MFMA16(qf1, kf1, z);
                sacc[nc] = z;
            }

            for (int nc = 0; nc < 8; ++nc)
                for (int r = 0; r < 4; ++r)
                    sacc[nc][r] *= 0.125f;
            if (kt2 * 128 + 127 > rowbase) {
                for (int nc = 0; nc < 8; ++nc)
                    for (int r = 0; r < 4; ++r) {
                        int row = rowbase + q * 4 + r;
                        int col = kt2 * 128 + nc * 16 + m;
                        if (col > row) sacc[nc][r] = NEG_BIG;
                    }
            }

            float mnew[4], alpha[4];
            for (int r = 0; r < 4; ++r) {
                float rm = sacc[0][r];
                for (int nc = 1; nc < 8; ++nc) rm = fmaxf(rm, sacc[nc][r]);
                rm = rowmax16(rm);
                mnew[r]  = fmaxf(mi[r], rm);
                alpha[r] = __expf(fmaxf(mi[r] - mnew[r], -80.f));
                mi[r]    = mnew[r];
            }
            for (int r = 0; r < 4; ++r) {
                float acc = 0.f;
                for (int nc = 0; nc < 8; ++nc) {
                    float p = __expf(fmaxf(sacc[nc][r] - mnew[r], -80.f));
                    sacc[nc][r] = p;
                    acc += p;
                }
                acc = rowsum16(acc);
                li[r] = li[r] * alpha[r] + acc;
                for (int nb = 0; nb < 4; ++nb) oacc[nb][r] *= alpha[r];
            }

            for (int nc = 0; nc < 8; ++nc)
                for (int r = 0; r < 4; ++r) {
                    bf16 hv = __float2bfloat16(sacc[nc][r]);
                    Ps[wave][(q * 4 + r) * VST + nc * 16 + m] = *(short*)&hv;
                }
            short8 pa[4];
            for (int ck = 0; ck < 4; ++ck)
                pa[ck] = *(const short8*)&Ps[wave][m * VST + ck * 32 + q * 8];

            for (int nb = 0; nb < 4; ++nb)
                for (int ck = 0; ck < 4; ++ck) {
                    short8 vf = *(const short8*)&Vs[(nb * 16 + m) * VST + ck * 32 + q * 8];
                    oacc[nb] = MFMA16(pa[ck], vf, oacc[nb]);
                }
        }

        for (int r = 0; r < 4; ++r) {
            float inv = 1.f / li[r];
            int srowg = qtile * 64 + wave * 16 + q * 4 + r;
            for (int nb = 0; nb < 4; ++nb)
                ctx[(b * 2048 + srowg) * 1024 + h * 64 + nb * 16 + m] =
                    __float2bfloat16(oacc[nb][r] * inv);
        }
        __syncthreads();
    }
}

// ---------------------------------------------------------------------------
// Kernel 3: output projection (round-10 proven structure).
// ---------------------------------------------------------------------------
__global__ __launch_bounds__(256) void gemm_out(
    const bf16* __restrict__ A,
    const void* __restrict__ wor, const bf16* __restrict__ Woc,
    const void* __restrict__ xr,
    void* __restrict__ out)
{
    const bool f32in = inputs_are_fp32((const unsigned short*)xr);
    const bf16* W = f32in ? Woc : (const bf16*)wor;

    __shared__ __align__(16) short As[64 * 40];
    __shared__ __align__(16) short Ws[64 * 40];

    const int m0 = blockIdx.x * 64;
    const int n0 = blockIdx.y * 64;
    const int tid  = threadIdx.x;
    const int lane = tid & 63;
    const int wave = tid >> 6;
    const int wr = wave >> 1, wc = wave & 1;
    const int srow = tid >> 2, sseg = tid & 3;
    const int fr = lane & 15, fq = lane >> 4;

    const bf16* Arow = A + (m0 + srow) * 1024 + sseg * 8;
    const bf16* Wrow = W + (n0 + srow) * 1024 + sseg * 8;

    f32x4 acc00 = {0.f,0.f,0.f,0.f}, acc01 = {0.f,0.f,0.f,0.f};
    f32x4 acc10 = {0.f,0.f,0.f,0.f}, acc11 = {0.f,0.f,0.f,0.f};

    short8 paa = *(const short8*)(Arow);
    short8 pwb = *(const short8*)(Wrow);

    for (int k0 = 0; k0 < 1024; k0 += 32) {
        __syncthreads();
        *(short8*)&As[srow * 40 + sseg * 8] = paa;
        *(short8*)&Ws[srow * 40 + sseg * 8] = pwb;
        __syncthreads();
        if (k0 + 32 < 1024) {
            paa = *(const short8*)(Arow + k0 + 32);
            pwb = *(const short8*)(Wrow + k0 + 32);
        }
        short8 a0 = *(const short8*)&As[(wr * 32 +      fr) * 40 + fq * 8];
        short8 a1 = *(const short8*)&As[(wr * 32 + 16 + fr) * 40 + fq * 8];
        short8 b0 = *(const short8*)&Ws[(wc * 32 +      fr) * 40 + fq * 8];
        short8 b1 = *(const short8*)&Ws[(wc * 32 + 16 + fr) * 40 + fq * 8];
        acc00 = MFMA16(a0, b0, acc00);
        acc01 = MFMA16(a0, b1, acc01);
        acc10 = MFMA16(a1, b0, acc10);
        acc11 = MFMA16(a1, b1, acc11);
    }

    for (int i = 0; i < 2; ++i)
        for (int j = 0; j < 2; ++j) {
            f32x4 a = (i == 0) ? ((j == 0) ? acc00 : acc01)
                               : ((j == 0) ? acc10 : acc11);
            for (int r = 0; r < 4; ++r) {
                int gm = m0 + wr * 32 + i * 16 + fq * 4 + r;
                int gn = n0 + wc * 32 + j * 16 + fr;
                int idx = gm * 1024 + gn;
                if (f32in) ((float*)out)[idx] = a[r];
                else       ((bf16*)out)[idx]  = __float2bfloat16(a[r]);
            }
        }
}

// ---------------------------------------------------------------------------
extern "C" void kernel_launch(void* const* d_in, const int* in_sizes, int n_in,
                              void* d_out, int out_size, void* d_ws, size_t ws_size,
                              hipStream_t stream)
{
    const void* x_raw  = d_in[0];
    const void* Wq_raw = d_in[1];
    const void* Wk_raw = d_in[2];
    const void* Wv_raw = d_in[3];
    const void* Wo_raw = d_in[4];
    const int*  pos    = (const int*)d_in[5];

    char* ws = (char*)d_ws;
    bf16* Xc  = (bf16*)ws;                                    // 8 MB
    bf16* Wqc = (bf16*)(ws + 8388608);                        // 2 MB each
    bf16* Wkc = (bf16*)(ws + 8388608 + 2097152);
    bf16* Wvc = (bf16*)(ws + 8388608 + 2 * 2097152);
    bf16* Woc = (bf16*)(ws + 8388608 + 3 * 2097152);
    bf16* Qb  = (bf16*)(ws + 8388608 + 4 * 2097152);          // 8 MB each
    bf16* Kb  = Qb + 4194304;
    bf16* Vt  = Kb + 4194304;
    bf16* ctx = Vt + 4194304;
    float2* rtab = (float2*)(ctx + 4194304);                  // 512 KB

    rope_table<<<256, 256, 0, stream>>>(pos, rtab);
    convert_all<<<16384, 256, 0, stream>>>(
        x_raw, Wq_raw, Wk_raw, Wv_raw, Wo_raw,
        (unsigned int*)Xc, (unsigned int*)Wqc, (unsigned int*)Wkc,
        (unsigned int*)Wvc, (unsigned int*)Woc);

    gemm_qkv_rope<<<dim3(64, 48), 256, 0, stream>>>(
        x_raw, Wq_raw, Wk_raw, Wv_raw, Xc, Wqc, Wkc, Wvc, rtab, Qb, Kb, Vt);
    flash_attn<<<dim3(16, 16, 2), 256, 0, stream>>>(Qb, Kb, Vt, ctx);
    gemm_out<<<dim3(64, 16), 256, 0, stream>>>(ctx, Wo_raw, Woc, x_raw, d_out);
}

// Round 13
// 212.015 us; speedup vs baseline: 1.8947x; 1.0404x over previous
//
#include <hip/hip_runtime.h>
#include <hip/hip_bf16.h>
#include <math.h>

typedef __hip_bfloat16 bf16;
typedef __attribute__((ext_vector_type(8))) short short8;
typedef __attribute__((ext_vector_type(4))) float f32x4;

#define MFMA16(A, B, C) __builtin_amdgcn_mfma_f32_16x16x32_bf16((A), (B), (C), 0, 0, 0)
#define NEG_BIG (-1e30f)

// DPP row_ror rotate within 16-lane rows (VALU pipe — NOT LDS, unlike __shfl)
#define DPP_F(x, ctrl) \
    __int_as_float(__builtin_amdgcn_update_dpp(0, __float_as_int(x), (ctrl), 0xf, 0xf, false))

static __device__ __forceinline__ float rowsum16(float x) {
    x += DPP_F(x, 0x121);
    x += DPP_F(x, 0x122);
    x += DPP_F(x, 0x124);
    x += DPP_F(x, 0x128);
    return x;
}
static __device__ __forceinline__ float rowmax16(float x) {
    x = fmaxf(x, DPP_F(x, 0x121));
    x = fmaxf(x, DPP_F(x, 0x122));
    x = fmaxf(x, DPP_F(x, 0x124));
    x = fmaxf(x, DPP_F(x, 0x128));
    return x;
}

// fp32 -> bf16 round-to-nearest-even via bit ops
static __device__ __forceinline__ unsigned short f32_to_bf16_rne(float f) {
    unsigned int u = __float_as_uint(f);
    unsigned int rnd = 0x7FFFu + ((u >> 16) & 1u);
    return (unsigned short)((u + rnd) >> 16);
}

// In-kernel dtype detection (wave-uniform): scan first 64 shorts of x.
static __device__ __forceinline__ bool inputs_are_fp32(const unsigned short* x16) {
    int lane = threadIdx.x & 63;
    int e = (x16[lane] >> 7) & 0xFF;
    unsigned long long ball = __ballot(e >= 133);
    return __popcll(ball) >= 4;
}

// ---------------------------------------------------------------------------
// Kernel 0a: RoPE cos/sin table [s][p] float2, 2048 x 32 entries (512 KB).
// ---------------------------------------------------------------------------
__global__ __launch_bounds__(256) void rope_table(
    const int* __restrict__ pos, float2* __restrict__ tab)
{
    int i = blockIdx.x * 256 + threadIdx.x;   // 0..65535
    int s = i >> 5, p = i & 31;
    float freq = __expf((float)p * -0.28782313662425575f);
    float ang  = (float)pos[s] * freq;
    float sn, c;
    sincosf(ang, &sn, &c);
    tab[i] = make_float2(c, sn);
}

// ---------------------------------------------------------------------------
// Kernel 0b: canonical bf16 copies of all 5 inputs (fp32 path only).
// ---------------------------------------------------------------------------
__global__ __launch_bounds__(256) void convert_all(
    const void* __restrict__ xs, const void* __restrict__ wq,
    const void* __restrict__ wk, const void* __restrict__ wv,
    const void* __restrict__ wo,
    unsigned int* __restrict__ Xc, unsigned int* __restrict__ Wqc,
    unsigned int* __restrict__ Wkc, unsigned int* __restrict__ Wvc,
    unsigned int* __restrict__ Woc)
{
    if (!inputs_are_fp32((const unsigned short*)xs)) return;
    int i = blockIdx.x * 256 + threadIdx.x;  // 0 .. 4194303
    const float* src;
    unsigned int* dst;
    int off;
    if (i < 2097152) { src = (const float*)xs; dst = Xc; off = i; }
    else {
        int j = i - 2097152;
        int t = j >> 19;          // 0..3
        off = j & 524287;
        src = (const float*)((t == 0) ? wq : (t == 1) ? wk : (t == 2) ? wv : wo);
        dst = (t == 0) ? Wqc : (t == 1) ? Wkc : (t == 2) ? Wvc : Woc;
    }
    unsigned int lo = f32_to_bf16_rne(src[2 * off]);
    unsigned int hi = f32_to_bf16_rne(src[2 * off + 1]);
    dst[off] = (hi << 16) | lo;
}

// ---------------------------------------------------------------------------
// Kernel 1: QKV projection GEMM, 128x128 tile (m93-rung), BK=32,
// ds_write staging + register prefetch, stride-40 padded LDS.
// __launch_bounds__(256,1): allow ~256 VGPR, NO accumulator spill.
// grid = (32 m-tiles, 24 = 3 weights x 8 n-tiles), block = 256 (2x2 waves).
// Q,K: RoPE-table epilogue [b,h,s,d]. V: LDS-transposed [b,h,d,s].
// ---------------------------------------------------------------------------
__global__ __launch_bounds__(256, 1) void gemm_qkv_rope(
    const void* __restrict__ xr,
    const void* __restrict__ wqr, const void* __restrict__ wkr,
    const void* __restrict__ wvr,
    const bf16* __restrict__ Xc,
    const bf16* __restrict__ Wqc, const bf16* __restrict__ Wkc,
    const bf16* __restrict__ Wvc,
    const float2* __restrict__ rtab,
    bf16* __restrict__ Qb, bf16* __restrict__ Kb, bf16* __restrict__ Vt)
{
    const bool f32in = inputs_are_fp32((const unsigned short*)xr);
    const bf16* X = f32in ? Xc : (const bf16*)xr;

    // union: staging (2 x 128x40) vs V-transpose tile (128x132)
    __shared__ __align__(16) short smem[128 * 132];   // 33792 B
    short* As = smem;              // [128][40]
    short* Bs = smem + 5120;       // [128][40]

    const int m0   = blockIdx.x * 128;
    const int wsel = blockIdx.y >> 3;            // 0=Q, 1=K, 2=V
    const int n0   = (blockIdx.y & 7) * 128;
    const bf16* W  = (wsel == 0) ? (f32in ? Wqc : (const bf16*)wqr)
                   : (wsel == 1) ? (f32in ? Wkc : (const bf16*)wkr)
                                 : (f32in ? Wvc : (const bf16*)wvr);

    const int tid  = threadIdx.x;
    const int lane = tid & 63;
    const int wave = tid >> 6;
    const int wr   = wave >> 1, wc = wave & 1;   // 2x2 waves, each 64x64
    const int m    = lane & 15;
    const int q    = lane >> 4;

    // staging: thread t -> rows tid>>2 and (tid>>2)+64, seg tid&3
    const int srow = tid >> 2;            // 0..63
    const int sseg = tid & 3;
    const bf16* Ag = X + (m0 + srow) * 1024 + sseg * 8;
    const bf16* Bg = W + (n0 + srow) * 1024 + sseg * 8;

    f32x4 acc[4][4];
    #pragma unroll
    for (int mi = 0; mi < 4; ++mi)
        #pragma unroll
        for (int ni = 0; ni < 4; ++ni)
            acc[mi][ni] = (f32x4){0.f, 0.f, 0.f, 0.f};

    short8 pa0 = *(const short8*)(Ag);
    short8 pa1 = *(const short8*)(Ag + 64 * 1024);
    short8 pb0 = *(const short8*)(Bg);
    short8 pb1 = *(const short8*)(Bg + 64 * 1024);

    for (int k0 = 0; k0 < 1024; k0 += 32) {
        __syncthreads();
        *(short8*)&As[srow * 40 + sseg * 8]        = pa0;
        *(short8*)&As[(srow + 64) * 40 + sseg * 8] = pa1;
        *(short8*)&Bs[srow * 40 + sseg * 8]        = pb0;
        *(short8*)&Bs[(srow + 64) * 40 + sseg * 8] = pb1;
        __syncthreads();
        if (k0 + 32 < 1024) {
            pa0 = *(const short8*)(Ag + k0 + 32);
            pa1 = *(const short8*)(Ag + 64 * 1024 + k0 + 32);
            pb0 = *(const short8*)(Bg + k0 + 32);
            pb1 = *(const short8*)(Bg + 64 * 1024 + k0 + 32);
        }

        short8 af[4], bf[4];
        #pragma unroll
        for (int mi = 0; mi < 4; ++mi)
            af[mi] = *(const short8*)&As[(wr * 64 + mi * 16 + m) * 40 + q * 8];
        #pragma unroll
        for (int ni = 0; ni < 4; ++ni)
            bf[ni] = *(const short8*)&Bs[(wc * 64 + ni * 16 + m) * 40 + q * 8];
        #pragma unroll
        for (int mi = 0; mi < 4; ++mi)
            #pragma unroll
            for (int ni = 0; ni < 4; ++ni)
                acc[mi][ni] = MFMA16(af[mi], bf[ni], acc[mi][ni]);
    }

    const int bb  = m0 >> 11;
    const int s0  = m0 & 2047;
    const int hh0 = n0 >> 6;          // first of 2 heads in this n-tile

    if (wsel < 2) {
        bf16* dstb = (wsel == 0) ? Qb : Kb;
        #pragma unroll
        for (int mi = 0; mi < 4; ++mi)
            #pragma unroll
            for (int ni = 0; ni < 4; ++ni)
                #pragma unroll
                for (int r = 0; r < 4; ++r) {
                    int s  = s0 + wr * 64 + mi * 16 + q * 4 + r;
                    int gn = n0 + wc * 64 + ni * 16 + m;
                    int h = gn >> 6, d = gn & 63;
                    float v = acc[mi][ni][r];
                    float partner = __shfl_xor(v, 1);
                    float2 cs = rtab[s * 32 + (d >> 1)];
                    float outv = ((d & 1) == 0) ? (cs.x * v - cs.y * partner)
                                                : (cs.y * partner + cs.x * v);
                    dstb[((bb * 16 + h) * 2048 + s) * 64 + d] = __float2bfloat16(outv);
                }
    } else {
        __syncthreads();   // all As/Bs reads done before alias overwrite
        #pragma unroll
        for (int mi = 0; mi < 4; ++mi)
            #pragma unroll
            for (int ni = 0; ni < 4; ++ni)
                #pragma unroll
                for (int r = 0; r < 4; ++r) {
                    int ls = wr * 64 + mi * 16 + q * 4 + r;   // local s 0..127
                    int ld = wc * 64 + ni * 16 + m;           // local d 0..127
                    bf16 hv = __float2bfloat16(acc[mi][ni][r]);
                    smem[ld * 132 + ls] = *(short*)&hv;
                }
        __syncthreads();
        int dd = tid >> 1;            // 0..127: head hh0 + (dd>>6), d = dd&63
        int half = tid & 1;
        bf16* vrow = Vt + ((bb * 16 + hh0 + (dd >> 6)) * 64 + (dd & 63)) * 2048
                        + s0 + half * 64;
        #pragma unroll
        for (int j = 0; j < 8; ++j)
            *(short8*)(vrow + j * 8) =
                *(const short8*)&smem[dd * 132 + half * 64 + j * 8];
    }
}

// ---------------------------------------------------------------------------
// Kernel 2: causal flash attention (round-10 proven, unchanged).
// ---------------------------------------------------------------------------
#define KST 72
#define VST 136

__global__ __launch_bounds__(256) void flash_attn(
    const bf16* __restrict__ Qb, const bf16* __restrict__ Kb,
    const bf16* __restrict__ Vt, bf16* __restrict__ ctx)
{
    const int pair = blockIdx.x;      // 0..15
    const int h = blockIdx.y, b = blockIdx.z;
    const int bh = b * 16 + h;

    __shared__ __align__(16) short Ks[128 * KST];
    __shared__ __align__(16) short Vs[64 * VST];
    __shared__ __align__(16) short Ps[4][16 * VST];

    const int tid  = threadIdx.x;
    const int lane = tid & 63;
    const int wave = tid >> 6;
    const int m = lane & 15;
    const int q = lane >> 4;

    const int krow = tid >> 1;
    const int kseg = (tid & 1) * 32;
    const int vrow = tid >> 2;
    const int vseg = (tid & 3) * 32;

    const bf16* Kg = Kb + bh * 2048 * 64 + krow * 64   + kseg;
    const bf16* Vg = Vt + bh * 64 * 2048 + vrow * 2048 + vseg;

    for (int part = 0; part < 2; ++part) {
        const int qtile = (part == 0) ? pair : 31 - pair;
        const int nk2 = (qtile + 2) >> 1;
        const int rowbase = qtile * 64 + wave * 16;

        const bf16* Qp = Qb + (bh * 2048 + qtile * 64 + wave * 16 + m) * 64;
        short8 qf0 = *(const short8*)(Qp + q * 8);
        short8 qf1 = *(const short8*)(Qp + 32 + q * 8);

        f32x4 oacc[4];
        #pragma unroll
        for (int nb = 0; nb < 4; ++nb) oacc[nb] = (f32x4){0.f, 0.f, 0.f, 0.f};
        float mi[4], li[4];
        #pragma unroll
        for (int r = 0; r < 4; ++r) { mi[r] = NEG_BIG; li[r] = 0.f; }

        short8 kr[4], vr[4];
        #pragma unroll
        for (int j = 0; j < 4; ++j) {
            kr[j] = *(const short8*)(Kg + j * 8);
            vr[j] = *(const short8*)(Vg + j * 8);
        }

        for (int kt2 = 0; kt2 < nk2; ++kt2) {
            __syncthreads();
            #pragma unroll
            for (int j = 0; j < 4; ++j) {
                *(short8*)&Ks[krow * KST + kseg + j * 8] = kr[j];
                *(short8*)&Vs[vrow * VST + vseg + j * 8] = vr[j];
            }
            __syncthreads();

            if (kt2 + 1 < nk2) {
                #pragma unroll
                for (int j = 0; j < 4; ++j) {
                    kr[j] = *(const short8*)(Kg + (kt2 + 1) * 8192 + j * 8);
                    vr[j] = *(const short8*)(Vg + (kt2 + 1) * 128  + j * 8);
                }
            }

            f32x4 sacc[8];
            #pragma unroll
            for (int nc = 0; nc < 8; ++nc) {
                short8 kf0 = *(const short8*)&Ks[(nc * 16 + m) * KST + q * 8];
                short8 kf1 = *(const short8*)&Ks[(nc * 16 + m) * KST + 32 + q * 8];
                f32x4 z = {0.f, 0.f, 0.f, 0.f};
                z = MFMA16(qf0, kf0, z);
                z = MFMA16(qf1, kf1, z);
                sacc[nc] = z;
            }

            #pragma unroll
            for (int nc = 0; nc < 8; ++nc)
                #pragma unroll
                for (int r = 0; r < 4; ++r)
                    sacc[nc][r] *= 0.125f;
            if (kt2 * 128 + 127 > rowbase) {
                #pragma unroll
                for (int nc = 0; nc < 8; ++nc)
                    #pragma unroll
                    for (int r = 0; r < 4; ++r) {
                        int row = rowbase + q * 4 + r;
                        int col = kt2 * 128 + nc * 16 + m;
                        if (col > row) sacc[nc][r] = NEG_BIG;
                    }
            }

            float mnew[4], alpha[4];
            #pragma unroll
            for (int r = 0; r < 4; ++r) {
                float rm = sacc[0][r];
                #pragma unroll
                for (int nc = 1; nc < 8; ++nc) rm = fmaxf(rm, sacc[nc][r]);
                rm = rowmax16(rm);
                mnew[r]  = fmaxf(mi[r], rm);
                alpha[r] = __expf(fmaxf(mi[r] - mnew[r], -80.f));
                mi[r]    = mnew[r];
            }
            #pragma unroll
            for (int r = 0; r < 4; ++r) {
                float acc = 0.f;
                #pragma unroll
                for (int nc = 0; nc < 8; ++nc) {
                    float p = __expf(fmaxf(sacc[nc][r] - mnew[r], -80.f));
                    sacc[nc][r] = p;
                    acc += p;
                }
                acc = rowsum16(acc);
                li[r] = li[r] * alpha[r] + acc;
                #pragma unroll
                for (int nb = 0; nb < 4; ++nb) oacc[nb][r] *= alpha[r];
            }

            #pragma unroll
            for (int nc = 0; nc < 8; ++nc)
                #pragma unroll
                for (int r = 0; r < 4; ++r) {
                    bf16 hv = __float2bfloat16(sacc[nc][r]);
                    Ps[wave][(q * 4 + r) * VST + nc * 16 + m] = *(short*)&hv;
                }
            short8 pa[4];
            #pragma unroll
            for (int ck = 0; ck < 4; ++ck)
                pa[ck] = *(const short8*)&Ps[wave][m * VST + ck * 32 + q * 8];

            #pragma unroll
            for (int nb = 0; nb < 4; ++nb)
                #pragma unroll
                for (int ck = 0; ck < 4; ++ck) {
                    short8 vf = *(const short8*)&Vs[(nb * 16 + m) * VST + ck * 32 + q * 8];
                    oacc[nb] = MFMA16(pa[ck], vf, oacc[nb]);
                }
        }

        #pragma unroll
        for (int r = 0; r < 4; ++r) {
            float inv = 1.f / li[r];
            int srowg = qtile * 64 + wave * 16 + q * 4 + r;
            #pragma unroll
            for (int nb = 0; nb < 4; ++nb)
                ctx[(b * 2048 + srowg) * 1024 + h * 64 + nb * 16 + m] =
                    __float2bfloat16(oacc[nb][r] * inv);
        }
        __syncthreads();
    }
}

// ---------------------------------------------------------------------------
// Kernel 3: output projection, 128x128 tile, same anti-spill treatment.
// grid = (32, 8), block = 256.
// ---------------------------------------------------------------------------
__global__ __launch_bounds__(256, 1) void gemm_out(
    const bf16* __restrict__ A,
    const void* __restrict__ wor, const bf16* __restrict__ Woc,
    const void* __restrict__ xr,
    void* __restrict__ out)
{
    const bool f32in = inputs_are_fp32((const unsigned short*)xr);
    const bf16* W = f32in ? Woc : (const bf16*)wor;

    __shared__ __align__(16) short As[128 * 40];
    __shared__ __align__(16) short Bs[128 * 40];

    const int m0 = blockIdx.x * 128;
    const int n0 = blockIdx.y * 128;
    const int tid  = threadIdx.x;
    const int lane = tid & 63;
    const int wave = tid >> 6;
    const int wr = wave >> 1, wc = wave & 1;
    const int m = lane & 15, q = lane >> 4;
    const int srow = tid >> 2, sseg = tid & 3;

    const bf16* Ag = A + (m0 + srow) * 1024 + sseg * 8;
    const bf16* Bg = W + (n0 + srow) * 1024 + sseg * 8;

    f32x4 acc[4][4];
    #pragma unroll
    for (int mi = 0; mi < 4; ++mi)
        #pragma unroll
        for (int ni = 0; ni < 4; ++ni)
            acc[mi][ni] = (f32x4){0.f, 0.f, 0.f, 0.f};

    short8 pa0 = *(const short8*)(Ag);
    short8 pa1 = *(const short8*)(Ag + 64 * 1024);
    short8 pb0 = *(const short8*)(Bg);
    short8 pb1 = *(const short8*)(Bg + 64 * 1024);

    for (int k0 = 0; k0 < 1024; k0 += 32) {
        __syncthreads();
        *(short8*)&As[srow * 40 + sseg * 8]        = pa0;
        *(short8*)&As[(srow + 64) * 40 + sseg * 8] = pa1;
        *(short8*)&Bs[srow * 40 + sseg * 8]        = pb0;
        *(short8*)&Bs[(srow + 64) * 40 + sseg * 8] = pb1;
        __syncthreads();
        if (k0 + 32 < 1024) {
            pa0 = *(const short8*)(Ag + k0 + 32);
            pa1 = *(const short8*)(Ag + 64 * 1024 + k0 + 32);
            pb0 = *(const short8*)(Bg + k0 + 32);
            pb1 = *(const short8*)(Bg + 64 * 1024 + k0 + 32);
        }

        short8 af[4], bf[4];
        #pragma unroll
        for (int mi = 0; mi < 4; ++mi)
            af[mi] = *(const short8*)&As[(wr * 64 + mi * 16 + m) * 40 + q * 8];
        #pragma unroll
        for (int ni = 0; ni < 4; ++ni)
            bf[ni] = *(const short8*)&Bs[(wc * 64 + ni * 16 + m) * 40 + q * 8];
        #pragma unroll
        for (int mi = 0; mi < 4; ++mi)
            #pragma unroll
            for (int ni = 0; ni < 4; ++ni)
                acc[mi][ni] = MFMA16(af[mi], bf[ni], acc[mi][ni]);
    }

    #pragma unroll
    for (int mi = 0; mi < 4; ++mi)
        #pragma unroll
        for (int ni = 0; ni < 4; ++ni)
            #pragma unroll
            for (int r = 0; r < 4; ++r) {
                int gm = m0 + wr * 64 + mi * 16 + q * 4 + r;
                int gn = n0 + wc * 64 + ni * 16 + m;
                int idx = gm * 1024 + gn;
                if (f32in) ((float*)out)[idx] = acc[mi][ni][r];
                else       ((bf16*)out)[idx]  = __float2bfloat16(acc[mi][ni][r]);
            }
}

// ---------------------------------------------------------------------------
extern "C" void kernel_launch(void* const* d_in, const int* in_sizes, int n_in,
                              void* d_out, int out_size, void* d_ws, size_t ws_size,
                              hipStream_t stream)
{
    const void* x_raw  = d_in[0];
    const void* Wq_raw = d_in[1];
    const void* Wk_raw = d_in[2];
    const void* Wv_raw = d_in[3];
    const void* Wo_raw = d_in[4];
    const int*  pos    = (const int*)d_in[5];

    char* ws = (char*)d_ws;
    bf16* Xc  = (bf16*)ws;                                    // 8 MB
    bf16* Wqc = (bf16*)(ws + 8388608);                        // 2 MB each
    bf16* Wkc = (bf16*)(ws + 8388608 + 2097152);
    bf16* Wvc = (bf16*)(ws + 8388608 + 2 * 2097152);
    bf16* Woc = (bf16*)(ws + 8388608 + 3 * 2097152);
    bf16* Qb  = (bf16*)(ws + 8388608 + 4 * 2097152);          // 8 MB each
    bf16* Kb  = Qb + 4194304;
    bf16* Vt  = Kb + 4194304;
    bf16* ctx = Vt + 4194304;
    float2* rtab = (float2*)(ctx + 4194304);                  // 512 KB

    rope_table<<<256, 256, 0, stream>>>(pos, rtab);
    convert_all<<<16384, 256, 0, stream>>>(
        x_raw, Wq_raw, Wk_raw, Wv_raw, Wo_raw,
        (unsigned int*)Xc, (unsigned int*)Wqc, (unsigned int*)Wkc,
        (unsigned int*)Wvc, (unsigned int*)Woc);

    gemm_qkv_rope<<<dim3(32, 24), 256, 0, stream>>>(
        x_raw, Wq_raw, Wk_raw, Wv_raw, Xc, Wqc, Wkc, Wvc, rtab, Qb, Kb, Vt);
    flash_attn<<<dim3(16, 16, 2), 256, 0, stream>>>(Qb, Kb, Vt, ctx);
    gemm_out<<<dim3(32, 8), 256, 0, stream>>>(ctx, Wo_raw, Woc, x_raw, d_out);
}